// Round 3
// baseline (288.274 us; speedup 1.0000x reference)
//
#include <hip/hip_runtime.h>

#define N_NODES 100000
#define N_EDGES 1600000
#define D_FEAT  64

#define RSHIFT 8
#define RPB    256                              // rows per bucket
#define NBK    ((N_NODES + RPB - 1) / RPB)      // 391 row-buckets
#define CAP    5120                             // bucket edge capacity (even; 16B-aligned base)
#define EPB    4096                             // edges per bin block
#define KBLK   ((N_EDGES + EPB - 1) / EPB)      // 391 bin blocks
#define OROW   (NBK + 1)
#define CVB    ((N_NODES * D_FEAT / 4 + 1023) / 1024)  // 1563 convert blocks

typedef float f32x2 __attribute__((ext_vector_type(2)));
typedef int   i32x4 __attribute__((ext_vector_type(4)));
typedef float f32x4 __attribute__((ext_vector_type(4)));

__device__ __forceinline__ unsigned short f2bf(float f) {
  union { float f; unsigned int i; } v; v.f = f;
  unsigned int b = v.i;
  return (unsigned short)((b + 0x7FFFu + ((b >> 16) & 1u)) >> 16);  // RNE
}
__device__ __forceinline__ float ulo(int u) { return __int_as_float(u << 16); }
__device__ __forceinline__ float uhi(int u) { return __int_as_float(u & 0xFFFF0000); }
__device__ __forceinline__ f32x2 upk(int u) {  // {elem0, elem1} of a bf16 pair
  f32x2 r; r.x = ulo(u); r.y = uhi(u); return r;
}
__device__ __forceinline__ int pk(float a, float b) {
  return (int)f2bf(a) | ((int)f2bf(b) << 16);
}
// nontemporal 16B load/store (keep streaming data out of L2 so x stays hot)
__device__ __forceinline__ int4 ntl4(const int4* p) {
  i32x4 r = __builtin_nontemporal_load((const i32x4*)p);
  int4 o; o.x = r.x; o.y = r.y; o.z = r.z; o.w = r.w; return o;
}
__device__ __forceinline__ void nts4i(int4* p, int4 v) {
  i32x4 t; t.x = v.x; t.y = v.y; t.z = v.z; t.w = v.w;
  __builtin_nontemporal_store(t, (i32x4*)p);
}
__device__ __forceinline__ void nts4f(float4* p, float4 v) {
  f32x4 t; t.x = v.x; t.y = v.y; t.z = v.z; t.w = v.w;
  __builtin_nontemporal_store(t, (f32x4*)p);
}

// ---- fused: blocks [0,KBLK) bin edges; blocks [KBLK, KBLK+CVB) convert x ----
__global__ __launch_bounds__(1024) void convert_bin(
    const float4* __restrict__ xin, ushort4* __restrict__ xout,
    const int* __restrict__ erow, const int* __restrict__ ecol,
    const float* __restrict__ evals, int2* __restrict__ tmp,
    int* __restrict__ offs) {
  __shared__ int hist[NBK];
  __shared__ int sc[NBK];
  int t = threadIdx.x;
  int k = blockIdx.x;
  if (k >= KBLK) {                       // ---- convert path ----
    int i = (k - KBLK) * 1024 + t;
    if (i < N_NODES * D_FEAT / 4) {
      float4 v = xin[i];
      ushort4 o;
      o.x = f2bf(v.x); o.y = f2bf(v.y); o.z = f2bf(v.z); o.w = f2bf(v.w);
      xout[i] = o;
    }
    return;
  }
  // ---- bin path: block-local counting sort of 4096 edges by bucket ----
  if (t < NBK) hist[t] = 0;
  __syncthreads();
  int base = k * EPB;
  int nk = N_EDGES - base; if (nk > EPB) nk = EPB;
  int key[4], vb[4], rk[4], bk[4];
#pragma unroll
  for (int j = 0; j < 4; ++j) {
    int li = j * 1024 + t;
    bk[j] = -1;
    if (li < nk) {
      int e = base + li;
      int r = erow[e];
      key[j] = ((r & (RPB - 1)) << 17) | ecol[e];
      vb[j]  = __float_as_int(evals[e]);
      bk[j]  = r >> RSHIFT;
      rk[j]  = atomicAdd(&hist[bk[j]], 1);
    }
  }
  __syncthreads();
  if (t < NBK) sc[t] = hist[t];
  __syncthreads();
  for (int off = 1; off < NBK; off <<= 1) {
    int u = (t >= off && t < NBK) ? sc[t - off] : 0;
    __syncthreads();
    if (t < NBK) sc[t] += u;
    __syncthreads();
  }
  if (t < NBK) {
    int ex = sc[t] - hist[t];
    sc[t] = ex;
    offs[k * OROW + t] = ex;
  }
  if (t == 0) offs[k * OROW + NBK] = nk;
  __syncthreads();
#pragma unroll
  for (int j = 0; j < 4; ++j) {
    if (bk[j] >= 0) {
      int pos = sc[bk[j]] + rk[j];
      tmp[k * EPB + pos] = make_int2(key[j], vb[j]);
    }
  }
}

// ---- pass 2: octet-per-run sweep, 512 threads. Rows padded to EVEN edge
// counts so every row starts 16B-aligned in the edge array.
__global__ __launch_bounds__(512) void build_csr(
    const int2* __restrict__ tmp, const int* __restrict__ offs,
    int2* __restrict__ edges, int* __restrict__ row_beg,
    int* __restrict__ row_end) {
  __shared__ int hist[RPB];
  __shared__ int cur[RPB];
  int b = blockIdx.x;
  int t = threadIdx.x;
  int oct = t >> 3;        // 64 octets per block
  int ol  = t & 7;
  if (t < RPB) hist[t] = 0;
  __syncthreads();
  for (int k = oct; k < KBLK; k += 64) {
    int o0 = offs[k * OROW + b];
    int o1 = offs[k * OROW + b + 1];
    const int2* seg = tmp + k * EPB;
    for (int i = o0 + ol; i < o1; i += 8)
      atomicAdd(&hist[seg[i].x >> 17], 1);
  }
  __syncthreads();
  int v = 0, v2 = 0;
  if (t < RPB) {
    v  = hist[t];
    v2 = (v + 1) & ~1;     // even-padded length
    cur[t] = v2;
  }
  __syncthreads();
  for (int off = 1; off < RPB; off <<= 1) {
    int u = (t >= off && t < RPB) ? cur[t - off] : 0;
    __syncthreads();
    if (t < RPB) cur[t] += u;
    __syncthreads();
  }
  int excl2 = 0;
  int base = b * CAP;
  if (t < RPB) {
    excl2 = cur[t] - v2;
    int gr = b * RPB + t;
    if (gr < N_NODES) {
      row_beg[gr] = base + excl2;
      row_end[gr] = base + excl2 + v;
    }
    if (v & 1) edges[base + excl2 + v] = make_int2(0, 0);  // zero pad slot
  }
  __syncthreads();
  if (t < RPB) cur[t] = excl2;
  __syncthreads();
  for (int k = oct; k < KBLK; k += 64) {
    int o0 = offs[k * OROW + b];
    int o1 = offs[k * OROW + b + 1];
    const int2* seg = tmp + k * EPB;
    for (int i = o0 + ol; i < o1; i += 8) {
      int2 ed = seg[i];
      int pos = atomicAdd(&cur[ed.x >> 17], 1);
      edges[base + pos] = make_int2(ed.x & 0x1FFFF, ed.y);
    }
  }
}

// ---- sort each row's edges by column (in-register bitonic-64, one wave/row).
// Purpose: co-resident waves then sweep columns low->high in rough lockstep,
// shrinking the instantaneous gather window to a few MB (fits per-XCD L2).
// Pure optimization: any permutation within a row is correct (pad {0,0}
// sorts to front, still adds 0; rows >64 slots left unsorted = still correct).
__global__ __launch_bounds__(256) void sort_rows(
    const int* __restrict__ row_beg, const int* __restrict__ row_end,
    int2* __restrict__ edges) {
  int t = threadIdx.x;
  int lane = t & 63;
  int w = blockIdx.x * 4 + (t >> 6);   // wave id == row; grid exact 25000*4
  int e0 = row_beg[w];
  int e1 = row_end[w];
  int len2 = (e1 - e0 + 1) & ~1;       // even-padded length (includes pad slot)
  if (len2 > 64) return;               // wave-uniform guard (vanishingly rare)
  int k = 0x7FFFFFFF, v = 0;
  if (lane < len2) { int2 ed = edges[e0 + lane]; k = ed.x; v = ed.y; }
#pragma unroll
  for (int size = 2; size <= 64; size <<= 1) {
#pragma unroll
    for (int stride = size >> 1; stride >= 1; stride >>= 1) {
      int ok = __shfl_xor(k, stride);
      int ov = __shfl_xor(v, stride);
      bool up    = (lane & size) == 0;       // ascending subsequence?
      bool lower = (lane & stride) == 0;     // lower element of the pair?
      bool takeOther = (lower == up) ? (ok < k) : (ok > k);
      if (takeOther) { k = ok; v = ov; }
    }
  }
  if (lane < len2) edges[e0 + lane] = make_int2(k, v);
}

// ---- SpMM: ONE OCTET PER ROW (8 lanes x int4 = the full 128B feature row).
// 8 consecutive rows per wave, zero shuffles, zero LDS. Double-buffered
// software pipeline. All streaming accesses (edge pairs, residual adds,
// outputs) are NONTEMPORAL so the x gather table keeps L2 residency.
__global__ __launch_bounds__(256) void spmm_oct(
    const int* __restrict__ row_beg, const int* __restrict__ row_end,
    const int2* __restrict__ edges, const int4* __restrict__ xq,
    int4* __restrict__ h_q, float4* __restrict__ out,
    const int4* __restrict__ add1, const int4* __restrict__ add2,
    int final_mode) {
  int t = threadIdx.x;
  int lane = t & 63;
  int oct = lane >> 3;     // 0..7: row within wave
  int ol  = lane & 7;      // 0..7: which 16B of the 128B row
  int row = blockIdx.x * 32 + (t >> 6) * 8 + oct;   // grid exact: 3125*32=100000
  int e0 = row_beg[row];
  int e1 = row_end[row];
  const int4* ep = (const int4*)edges + (e0 >> 1);  // e0 even
  // Round UP: odd lengths include the (real, pad) pair; pad {0,0} adds 0.
  int npair = (e1 - e0 + 1) >> 1;
  f32x2 c0 = {0.f, 0.f}, c1 = {0.f, 0.f}, c2 = {0.f, 0.f}, c3 = {0.f, 0.f};

#define GATH(g0, g1, m) \
    g0 = xq[(size_t)(m).x * 8 + ol]; \
    g1 = xq[(size_t)(m).z * 8 + ol];
#define FMA_P(g0, g1, m) { \
    float v0 = __int_as_float((m).y), v1 = __int_as_float((m).w); \
    f32x2 vv0 = {v0, v0}, vv1 = {v1, v1}; \
    c0 += vv0 * upk((g0).x) + vv1 * upk((g1).x); \
    c1 += vv0 * upk((g0).y) + vv1 * upk((g1).y); \
    c2 += vv0 * upk((g0).z) + vv1 * upk((g1).z); \
    c3 += vv0 * upk((g0).w) + vv1 * upk((g1).w); \
  }

  if (npair >= 2) {
    int4 mA0 = ntl4(ep + 0), mA1 = ntl4(ep + 1);
    int4 a0, a1, a2, a3;
    GATH(a0, a1, mA0);
    GATH(a2, a3, mA1);
    int q = 2;
    while (q + 4 <= npair) {             // 2 blocks/iter: explicit A/B rotation
      int4 mB0 = ntl4(ep + q), mB1 = ntl4(ep + q + 1);
      int4 b0, b1, b2, b3;
      GATH(b0, b1, mB0);
      GATH(b2, b3, mB1);
      FMA_P(a0, a1, mA0);                // consume A (issued last iteration)
      FMA_P(a2, a3, mA1);
      mA0 = ntl4(ep + q + 2); mA1 = ntl4(ep + q + 3);
      GATH(a0, a1, mA0);
      GATH(a2, a3, mA1);
      FMA_P(b0, b1, mB0);                // consume B (issued this iteration)
      FMA_P(b2, b3, mB1);
      q += 4;
    }
    if (q + 2 <= npair) {                // one full block left
      int4 mB0 = ntl4(ep + q), mB1 = ntl4(ep + q + 1);
      int4 b0, b1, b2, b3;
      GATH(b0, b1, mB0);
      GATH(b2, b3, mB1);
      FMA_P(a0, a1, mA0);
      FMA_P(a2, a3, mA1);
      FMA_P(b0, b1, mB0);
      FMA_P(b2, b3, mB1);
      q += 2;
    } else {
      FMA_P(a0, a1, mA0);
      FMA_P(a2, a3, mA1);
    }
    if (q < npair) {                     // trailing single pair (odd npair)
      int4 m = ntl4(ep + q);
      int4 g0, g1;
      GATH(g0, g1, m);
      FMA_P(g0, g1, m);
    }
  } else if (npair == 1) {
    int4 m = ntl4(ep + 0);
    int4 g0, g1;
    GATH(g0, g1, m);
    FMA_P(g0, g1, m);
  }
#undef GATH
#undef FMA_P

  size_t oi = (size_t)row * 8 + ol;
  if (final_mode) {
    int4 r1 = ntl4(add1 + oi);
    int4 r2 = ntl4(add2 + oi);
    float4 lo, hi;
    lo.x = c0.x + ulo(r1.x) + ulo(r2.x);
    lo.y = c0.y + uhi(r1.x) + uhi(r2.x);
    lo.z = c1.x + ulo(r1.y) + ulo(r2.y);
    lo.w = c1.y + uhi(r1.y) + uhi(r2.y);
    hi.x = c2.x + ulo(r1.z) + ulo(r2.z);
    hi.y = c2.y + uhi(r1.z) + uhi(r2.z);
    hi.z = c3.x + ulo(r1.w) + ulo(r2.w);
    hi.w = c3.y + uhi(r1.w) + uhi(r2.w);
    nts4f(out + (size_t)row * 16 + ol * 2,     lo);
    nts4f(out + (size_t)row * 16 + ol * 2 + 1, hi);
  } else {
    int4 pq;
    pq.x = pk(c0.x, c0.y);
    pq.y = pk(c1.x, c1.y);
    pq.z = pk(c2.x, c2.y);
    pq.w = pk(c3.x, c3.y);
    nts4i(h_q + oi, pq);   // written once, read next layer from random XCD:
  }                        // keep it out of L2 so x stays resident
}

extern "C" void kernel_launch(void* const* d_in, const int* in_sizes, int n_in,
                              void* d_out, int out_size, void* d_ws, size_t ws_size,
                              hipStream_t stream) {
  const float* x     = (const float*)d_in[0];
  const int*   erow  = (const int*)d_in[1];
  const int*   ecol  = (const int*)d_in[2];
  const float* evals = (const float*)d_in[3];
  float* out = (float*)d_out;

  const size_t hb_bytes   = (size_t)N_NODES * D_FEAT * 2;     // 12.8 MB (bf16)
  const size_t ecap_bytes = (size_t)NBK * CAP * sizeof(int2); // 16.0 MB
  char* ws = (char*)d_ws;
  int4*    xbf  = (int4*)   (ws);                        // 12.8 MB, live whole launch
  int4*    bufA = (int4*)   (ws + hb_bytes);             // h1 (bf16)
  int2*    tmp  = (int2*)   (ws + hb_bytes);             // aliases bufA (build only)
  int4*    bufB = (int4*)   (ws + 2 * hb_bytes);         // h2 (bf16)
  int*     offs = (int*)    (ws + 2 * hb_bytes);         // aliases bufB (build only)
  int2* edges   = (int2*)(ws + 3 * hb_bytes);
  int* row_beg  = (int*) (ws + 3 * hb_bytes + ecap_bytes);
  int* row_end  = (int*) (ws + 3 * hb_bytes + ecap_bytes + 400000);

  const int sblocks = N_NODES / 32;                        // 3125 (8 rows/wave)

  // ---- fused convert + bin (1 dispatch), then CSR finalize, then col-sort --
  convert_bin<<<KBLK + CVB, 1024, 0, stream>>>(
      (const float4*)x, (ushort4*)xbf, erow, ecol, evals, tmp, offs);
  build_csr<<<NBK, 512, 0, stream>>>(tmp, offs, edges, row_beg, row_end);
  sort_rows<<<N_NODES / 4, 256, 0, stream>>>(row_beg, row_end, edges);

  // L1: bufA = bf16(A xbf)      (tmp dead after build)
  spmm_oct<<<sblocks, 256, 0, stream>>>(row_beg, row_end, edges, xbf,
                                        bufA, nullptr, nullptr, nullptr, 0);
  // L2: bufB = bf16(A bufA)     (offs dead)
  spmm_oct<<<sblocks, 256, 0, stream>>>(row_beg, row_end, edges, bufA,
                                        bufB, nullptr, nullptr, nullptr, 0);
  // L3: out = A bufB + bufA + bufB   (f32 output)
  spmm_oct<<<sblocks, 256, 0, stream>>>(row_beg, row_end, edges, bufB,
                                        nullptr, (float4*)out, bufA, bufB, 1);
}